// Round 24
// baseline (80.676 us; speedup 1.0000x reference)
//
#include <hip/hip_runtime.h>
#include <hip/hip_bf16.h>

#define H 4
#define C 32
#define CQ 128
#define NSEQ 256
#define HC 128   // H*C

typedef __bf16 bf16;
typedef __bf16 bf16x8 __attribute__((ext_vector_type(8)));
typedef __bf16 bf16x4 __attribute__((ext_vector_type(4)));
typedef float f32x4 __attribute__((ext_vector_type(4)));

#define MFMA16(a, b, c) __builtin_amdgcn_mfma_f32_16x16x32_bf16(a, b, c, 0, 0, 0)

#define LOG2E 1.4426950408889634f

__device__ __forceinline__ bf16x8 cvt8(float4 a, float4 b) {
    return (bf16x8){(bf16)a.x, (bf16)a.y, (bf16)a.z, (bf16)a.w,
                    (bf16)b.x, (bf16)b.y, (bf16)b.z, (bf16)b.w};
}

// ---------------------------------------------------------------------------
// Projection v6: ONE weight matrix per block (grid 256 x 4: q,g,k,v).
// LDS 104 KB -> 69.6 KB => 2 blocks/CU (4 waves/SIMD, double v5's TLP —
// proj was latency-bound at 17% occupancy). x-tiles re-staged by 2 blocks,
// but inputs are L3-resident (R23 FETCH 33.8 MB << 64 MB nominal).
// Weights converted f32->bf16 inline during staging (prep stays fused).
// m==0: q = (q_x@w_q^T)*(qscale*log2e); m==1: g = sigmoid(q_x@w_g^T);
// m==2: k = kv_x@w_k^T; m==3: v = kv_x@w_v^T.
// ---------------------------------------------------------------------------
__global__ __launch_bounds__(512) void proj_all(const float* __restrict__ qx,
                                                const float* __restrict__ kvx,
                                                const float* __restrict__ wqf,
                                                const float* __restrict__ wkf,
                                                const float* __restrict__ wvf,
                                                const float* __restrict__ wgf,
                                                bf16* __restrict__ qo,
                                                bf16* __restrict__ go,
                                                bf16* __restrict__ ko,
                                                bf16* __restrict__ vo) {
    __shared__ bf16 wsm[128][136];
    __shared__ bf16 xs[2][64][136];

    const int t = threadIdx.x;
    const int m = blockIdx.y;  // 0=q 1=g 2=k 3=v

    const float* x = (m < 2) ? qx : kvx;
    const float* wsrc = (m == 0) ? wqf : (m == 1) ? wgf : (m == 2) ? wkf : wvf;
    bf16* o = (m == 0) ? qo : (m == 1) ? go : (m == 2) ? ko : vo;

    const int row_blk = blockIdx.x * 256;
    const int sr = t >> 3, sc = (t & 7) * 16;  // staging coords: 8 thr/row

    // stage the weight matrix (f32 -> bf16 inline)
    #pragma unroll
    for (int i = t; i < 2048; i += 512) {
        int row = i >> 4, col = (i & 15) * 8;
        float4 a0 = *(const float4*)&wsrc[row * CQ + col];
        float4 a1 = *(const float4*)&wsrc[row * CQ + col + 4];
        *(bf16x8*)&wsm[row][col] = cvt8(a0, a1);
    }
    // stage x tile 0
    {
        const float* p = x + (size_t)(row_blk + sr) * CQ + sc;
        float4 v0 = *(const float4*)p, v1 = *(const float4*)(p + 4);
        float4 v2 = *(const float4*)(p + 8), v3 = *(const float4*)(p + 12);
        *(bf16x8*)&xs[0][sr][sc] = cvt8(v0, v1);
        *(bf16x8*)&xs[0][sr][sc + 8] = cvt8(v2, v3);
    }
    __syncthreads();

    const int w = t >> 6, l = t & 63, lr = l & 15, lg = l >> 4;

    // A-fragments: this wave's feature strip (read once)
    bf16x8 a[4];
    #pragma unroll
    for (int ks = 0; ks < 4; ks++)
        a[ks] = *(const bf16x8*)&wsm[w * 16 + lr][ks * 32 + lg * 8];

    const float qscale = 0.17677669529663687f * LOG2E;  // 1/sqrt(32) * log2e

    #pragma unroll 1
    for (int it = 0; it < 4; it++) {
        const int cur = it & 1;

        float4 n0, n1, n2, n3;
        if (it < 3) {
            const float* p = x + (size_t)(row_blk + (it + 1) * 64 + sr) * CQ + sc;
            n0 = *(const float4*)p;
            n1 = *(const float4*)(p + 4);
            n2 = *(const float4*)(p + 8);
            n3 = *(const float4*)(p + 12);
        }

        #pragma unroll
        for (int rt = 0; rt < 4; rt++) {
            bf16x8 b[4];
            #pragma unroll
            for (int ks = 0; ks < 4; ks++)
                b[ks] = *(const bf16x8*)&xs[cur][rt * 16 + lr][ks * 32 + lg * 8];

            f32x4 acc = (f32x4)0.f;
            #pragma unroll
            for (int ks = 0; ks < 4; ks++)
                acc = MFMA16(a[ks], b[ks], acc);

            bf16x4 st;
            #pragma unroll
            for (int r = 0; r < 4; r++) {
                float v = acc[r];
                if (m == 0) v *= qscale;
                else if (m == 1)
                    v = __builtin_amdgcn_rcpf(1.f + __builtin_amdgcn_exp2f(-v * LOG2E));
                st[r] = (bf16)v;
            }
            const size_t obase =
                (size_t)(row_blk + it * 64 + rt * 16 + lr) * HC + w * 16 + lg * 4;
            *(bf16x4*)&o[obase] = st;
        }

        if (it < 3) {
            *(bf16x8*)&xs[cur ^ 1][sr][sc] = cvt8(n0, n1);
            *(bf16x8*)&xs[cur ^ 1][sr][sc + 8] = cvt8(n2, n3);
        }
        __syncthreads();
    }
}

// ---------------------------------------------------------------------------
// Attention per (qc2, n1, h) — R21 VERBATIM (proven best): 512 thr, 8 waves,
// 1 q-tile/wave, non-swapped QK^T, no-max softmax with deferred
// normalization, PV in four 64-k quarters, XOR-swizzled vts.
// ---------------------------------------------------------------------------
__global__ __launch_bounds__(512) void attn_kernel(const bf16* __restrict__ qw,
                                                   const bf16* __restrict__ kw,
                                                   const bf16* __restrict__ vw,
                                                   const bf16* __restrict__ gw,
                                                   const float* __restrict__ pair_bias,
                                                   const float* __restrict__ mask_bias,
                                                   bf16* __restrict__ ow) {
    // bijective XCD swizzle over 2048 blocks
    const int wg = blockIdx.x;
    const int swz = ((wg & 7) << 8) + (wg >> 3);
    const int qc2 = swz & 1;
    const int n1 = (swz >> 1) & 255;
    const int h = swz >> 9;

    __shared__ bf16 klds[256][40];   // K slice [k][c], stride 20 dw
    __shared__ bf16 vts[32][256];    // V^T, col = k ^ 16*((c>>3)&3) ^ 8*(c&7)
    __shared__ bf16 ps[8][16][76];   // per-wave P tile, 64-k quarters

    const int t = threadIdx.x;

    // stage K (row-major head slice) and V^T (swizzled): 512 thr, 2 p-iters
    {
        const size_t base = ((size_t)n1 * NSEQ) * HC + (size_t)h * C;
        const int rr = t >> 2, cc4 = t & 3, ch = cc4 * 8;  // rr 0..127
        #pragma unroll
        for (int p = 0; p < 2; p++) {
            int row = p * 128 + rr;
            bf16x8 kv = *(const bf16x8*)&kw[base + (size_t)row * HC + ch];
            *(bf16x8*)&klds[row][ch] = kv;
            bf16x8 vv = *(const bf16x8*)&vw[base + (size_t)row * HC + ch];
            #pragma unroll
            for (int j = 0; j < 8; j++) {
                int colw = row ^ (cc4 << 4) ^ (j << 3);
                vts[ch + j][colw] = vv[j];
            }
        }
    }

    const int w = t >> 6, l = t & 63, lr = l & 15, lg = l >> 4;
    const int qbase = qc2 * 128 + w * 16;

    // Q fragment: A[q=lr][c = lg*8 + j]  (log2e pre-folded at projection)
    bf16x8 qf = *(const bf16x8*)&qw[((size_t)(n1 * NSEQ + qbase + lr)) * HC + h * C + lg * 8];

    const float* pb = pair_bias + (size_t)h * NSEQ * NSEQ;
    const float* mb = mask_bias + (size_t)n1 * NSEQ;

    // bias init before the barrier (pure VMEM, overlaps staging drain)
    f32x4 s[16];
    #pragma unroll
    for (int kt = 0; kt < 16; kt++) {
        float mbk = mb[kt * 16 + lr] * LOG2E;
        #pragma unroll
        for (int r = 0; r < 4; r++)
            s[kt][r] = fmaf(pb[(size_t)(qbase + lg * 4 + r) * NSEQ + kt * 16 + lr],
                            LOG2E, mbk);
    }

    __syncthreads();

    #pragma unroll
    for (int kt = 0; kt < 16; kt++) {
        bf16x8 kf = *(const bf16x8*)&klds[kt * 16 + lr][lg * 8];
        s[kt] = MFMA16(qf, kf, s[kt]);
    }

    // exp2 + row sums only (no max pass — R20-proven safe); P unnormalized
    float pinv[4];
    #pragma unroll
    for (int r = 0; r < 4; r++) {
        float sum = 0.f;
        #pragma unroll
        for (int kt = 0; kt < 16; kt++) {
            float e = __builtin_amdgcn_exp2f(s[kt][r]);
            s[kt][r] = e;
            sum += e;
        }
        #pragma unroll
        for (int msk = 8; msk >= 1; msk >>= 1) sum += __shfl_xor(sum, msk, 64);
        pinv[r] = __builtin_amdgcn_rcpf(sum);
    }

    // PV in four 64-k quarters via per-wave ps (same-wave, in-order);
    // P stored raw (normalization deferred to the gate)
    f32x4 o[2];
    o[0] = (f32x4)0.f;
    o[1] = (f32x4)0.f;
    #pragma unroll
    for (int qtr = 0; qtr < 4; qtr++) {
        #pragma unroll
        for (int kt2 = 0; kt2 < 4; kt2++) {
            #pragma unroll
            for (int r = 0; r < 4; r++)
                ps[w][lg * 4 + r][kt2 * 16 + lr] = (bf16)s[qtr * 4 + kt2][r];
        }
        #pragma unroll
        for (int kh = 0; kh < 2; kh++) {
            bf16x8 pf = *(const bf16x8*)&ps[w][lr][kh * 32 + lg * 8];
            #pragma unroll
            for (int ct = 0; ct < 2; ct++) {
                int g2 = (2 * ct + (lr >> 3)) & 3;
                int col0 = (qtr * 64 + kh * 32 + lg * 8) ^ (g2 << 4) ^ ((lr & 7) << 3);
                bf16x8 vf = *(const bf16x8*)&vts[ct * 16 + lr][col0];
                o[ct] = MFMA16(pf, vf, o[ct]);
            }
        }
    }

    // gate + deferred normalization + store head slice
    #pragma unroll
    for (int ct = 0; ct < 2; ct++) {
        #pragma unroll
        for (int r = 0; r < 4; r++) {
            size_t idx = ((size_t)(n1 * NSEQ + qbase + lg * 4 + r)) * HC + (size_t)h * C +
                         ct * 16 + lr;
            float gv = (float)gw[idx];
            ow[idx] = (bf16)(o[ct][r] * pinv[r] * gv);
        }
    }
}

// ---------------------------------------------------------------------------
// Output projection v5 (unchanged — proven R23): w_o staged f32->bf16 inline.
// ---------------------------------------------------------------------------
__global__ __launch_bounds__(512) void out_proj(const bf16* __restrict__ og,
                                                const float* __restrict__ wof,
                                                float* __restrict__ out) {
    __shared__ bf16 ws[128][136];
    __shared__ bf16 xs[2][64][136];

    const int t = threadIdx.x;
    const int row_blk = blockIdx.x * 256;
    const int sr = t >> 3, sc = (t & 7) * 16;

    #pragma unroll
    for (int i = t; i < 2048; i += 512) {
        int row = i >> 4, col = (i & 15) * 8;
        float4 a0 = *(const float4*)&wof[row * CQ + col];
        float4 a1 = *(const float4*)&wof[row * CQ + col + 4];
        *(bf16x8*)&ws[row][col] = cvt8(a0, a1);
    }
    {
        const bf16* p = og + (size_t)(row_blk + sr) * HC + sc;
        *(bf16x8*)&xs[0][sr][sc] = *(const bf16x8*)p;
        *(bf16x8*)&xs[0][sr][sc + 8] = *(const bf16x8*)(p + 8);
    }
    __syncthreads();

    const int w = t >> 6, l = t & 63, lr = l & 15, lg = l >> 4;

    bf16x8 a[4];
    #pragma unroll
    for (int ks = 0; ks < 4; ks++)
        a[ks] = *(const bf16x8*)&ws[w * 16 + lr][ks * 32 + lg * 8];

    #pragma unroll 1
    for (int it = 0; it < 4; it++) {
        const int cur = it & 1;

        bf16x8 m0, m1;
        if (it < 3) {
            const bf16* p = og + (size_t)(row_blk + (it + 1) * 64 + sr) * HC + sc;
            m0 = *(const bf16x8*)p;
            m1 = *(const bf16x8*)(p + 8);
        }

        #pragma unroll
        for (int rt = 0; rt < 4; rt++) {
            bf16x8 b[4];
            #pragma unroll
            for (int ks = 0; ks < 4; ks++)
                b[ks] = *(const bf16x8*)&xs[cur][rt * 16 + lr][ks * 32 + lg * 8];

            f32x4 acc = (f32x4)0.f;
            #pragma unroll
            for (int ks = 0; ks < 4; ks++)
                acc = MFMA16(a[ks], b[ks], acc);

            *(float4*)&out[(size_t)(row_blk + it * 64 + rt * 16 + lr) * CQ + w * 16 + lg * 4] =
                (float4){acc[0], acc[1], acc[2], acc[3]};
        }

        if (it < 3) {
            *(bf16x8*)&xs[cur ^ 1][sr][sc] = m0;
            *(bf16x8*)&xs[cur ^ 1][sr][sc + 8] = m1;
        }
        __syncthreads();
    }
}

// ---------------------------------------------------------------------------
extern "C" void kernel_launch(void* const* d_in, const int* in_sizes, int n_in,
                              void* d_out, int out_size, void* d_ws, size_t ws_size,
                              hipStream_t stream) {
    const float* q_x = (const float*)d_in[0];
    const float* kv_x = (const float*)d_in[1];
    const float* mask_bias = (const float*)d_in[2];
    const float* pair_bias = (const float*)d_in[3];
    const float* w_q = (const float*)d_in[4];
    const float* w_k = (const float*)d_in[5];
    const float* w_v = (const float*)d_in[6];
    const float* w_g = (const float*)d_in[7];
    const float* w_o = (const float*)d_in[8];

    const size_t M = (size_t)NSEQ * NSEQ;  // 65536
    bf16* qws = (bf16*)d_ws;
    bf16* gws = qws + M * HC;
    bf16* kws = gws + M * HC;
    bf16* vws = kws + M * HC;
    bf16* ows = vws + M * HC;

    proj_all<<<dim3(256, 4), 512, 0, stream>>>(q_x, kv_x, w_q, w_k, w_v, w_g,
                                               qws, gws, kws, vws);
    attn_kernel<<<dim3(2048), 512, 0, stream>>>(qws, kws, vws, gws, pair_bias,
                                                mask_bias, ows);
    out_proj<<<dim3(256), 512, 0, stream>>>(ows, w_o, (float*)d_out);
}

// Round 25
// 79.579 us; speedup vs baseline: 1.0138x; 1.0138x over previous
//
#include <hip/hip_runtime.h>
#include <hip/hip_bf16.h>

#define H 4
#define C 32
#define CQ 128
#define NSEQ 256
#define HC 128   // H*C

typedef __bf16 bf16;
typedef __bf16 bf16x8 __attribute__((ext_vector_type(8)));
typedef __bf16 bf16x4 __attribute__((ext_vector_type(4)));
typedef float f32x4 __attribute__((ext_vector_type(4)));

#define MFMA16(a, b, c) __builtin_amdgcn_mfma_f32_16x16x32_bf16(a, b, c, 0, 0, 0)

#define LOG2E 1.4426950408889634f

__device__ __forceinline__ bf16x8 cvt8(float4 a, float4 b) {
    return (bf16x8){(bf16)a.x, (bf16)a.y, (bf16)a.z, (bf16)a.w,
                    (bf16)b.x, (bf16)b.y, (bf16)b.z, (bf16)b.w};
}

// ---------------------------------------------------------------------------
// Dual projection (R23-final): both weight matrices staged f32->bf16 inline
// per block (no prep dispatch), swapped MFMA operands (A = weight strip, read
// once into registers), x-tiles double-buffered in LDS, bf16x4 stores.
// mode 0: q = (q_x@w_q^T)*(qscale*log2e), g = sigmoid(q_x@w_g^T)
// mode 1: k = kv_x@w_k^T, v = kv_x@w_v^T
// (R24's 1-matrix/block split doubled occupancy but regressed: duplicated
//  x staging + conflicts ate the TLP gain. Two-matrix version is optimal.)
// ---------------------------------------------------------------------------
__global__ __launch_bounds__(512) void proj_all(const float* __restrict__ qx,
                                                const float* __restrict__ kvx,
                                                const float* __restrict__ wqf,
                                                const float* __restrict__ wkf,
                                                const float* __restrict__ wvf,
                                                const float* __restrict__ wgf,
                                                bf16* __restrict__ qo,
                                                bf16* __restrict__ go,
                                                bf16* __restrict__ ko,
                                                bf16* __restrict__ vo) {
    __shared__ bf16 w1s[128][136];
    __shared__ bf16 w2s[128][136];
    __shared__ bf16 xs[2][64][136];

    const int t = threadIdx.x;
    const int mode = blockIdx.y;

    const float* x = mode ? kvx : qx;
    const float* w1 = mode ? wkf : wqf;
    const float* w2 = mode ? wvf : wgf;
    bf16* o1 = mode ? ko : qo;
    bf16* o2 = mode ? vo : go;

    const int row_blk = blockIdx.x * 256;
    const int sr = t >> 3, sc = (t & 7) * 16;  // staging coords: 8 thr/row

    // stage both weight matrices, converting f32 -> bf16 inline
    #pragma unroll
    for (int i = t; i < 2048; i += 512) {
        int row = i >> 4, col = (i & 15) * 8;
        float4 a0 = *(const float4*)&w1[row * CQ + col];
        float4 a1 = *(const float4*)&w1[row * CQ + col + 4];
        *(bf16x8*)&w1s[row][col] = cvt8(a0, a1);
        float4 b0 = *(const float4*)&w2[row * CQ + col];
        float4 b1 = *(const float4*)&w2[row * CQ + col + 4];
        *(bf16x8*)&w2s[row][col] = cvt8(b0, b1);
    }
    {
        const float* p = x + (size_t)(row_blk + sr) * CQ + sc;
        float4 v0 = *(const float4*)p, v1 = *(const float4*)(p + 4);
        float4 v2 = *(const float4*)(p + 8), v3 = *(const float4*)(p + 12);
        *(bf16x8*)&xs[0][sr][sc] = cvt8(v0, v1);
        *(bf16x8*)&xs[0][sr][sc + 8] = cvt8(v2, v3);
    }
    __syncthreads();

    const int w = t >> 6, l = t & 63, lr = l & 15, lg = l >> 4;

    bf16x8 a1[4], a2[4];
    #pragma unroll
    for (int ks = 0; ks < 4; ks++) {
        a1[ks] = *(const bf16x8*)&w1s[w * 16 + lr][ks * 32 + lg * 8];
        a2[ks] = *(const bf16x8*)&w2s[w * 16 + lr][ks * 32 + lg * 8];
    }

    const float qscale = 0.17677669529663687f * LOG2E;  // 1/sqrt(32) * log2e

    #pragma unroll 1
    for (int it = 0; it < 4; it++) {
        const int cur = it & 1;

        float4 n0, n1, n2, n3;
        if (it < 3) {
            const float* p = x + (size_t)(row_blk + (it + 1) * 64 + sr) * CQ + sc;
            n0 = *(const float4*)p;
            n1 = *(const float4*)(p + 4);
            n2 = *(const float4*)(p + 8);
            n3 = *(const float4*)(p + 12);
        }

        #pragma unroll
        for (int rt = 0; rt < 4; rt++) {
            bf16x8 b[4];
            #pragma unroll
            for (int ks = 0; ks < 4; ks++)
                b[ks] = *(const bf16x8*)&xs[cur][rt * 16 + lr][ks * 32 + lg * 8];

            f32x4 acc1 = (f32x4)0.f, acc2 = (f32x4)0.f;
            #pragma unroll
            for (int ks = 0; ks < 4; ks++) {
                acc1 = MFMA16(a1[ks], b[ks], acc1);
                acc2 = MFMA16(a2[ks], b[ks], acc2);
            }

            bf16x4 st1, st2;
            #pragma unroll
            for (int r = 0; r < 4; r++) {
                float v1 = acc1[r], v2 = acc2[r];
                if (mode == 0) {
                    v1 *= qscale;
                    v2 = __builtin_amdgcn_rcpf(1.f + __builtin_amdgcn_exp2f(-v2 * LOG2E));
                }
                st1[r] = (bf16)v1;
                st2[r] = (bf16)v2;
            }
            const size_t obase =
                (size_t)(row_blk + it * 64 + rt * 16 + lr) * HC + w * 16 + lg * 4;
            *(bf16x4*)&o1[obase] = st1;
            *(bf16x4*)&o2[obase] = st2;
        }

        if (it < 3) {
            *(bf16x8*)&xs[cur ^ 1][sr][sc] = cvt8(n0, n1);
            *(bf16x8*)&xs[cur ^ 1][sr][sc + 8] = cvt8(n2, n3);
        }
        __syncthreads();
    }
}

// ---------------------------------------------------------------------------
// Attention per (qc2, n1, h) — R21/R23 final: 512 thr, 8 waves, 1 q-tile per
// wave, non-swapped QK^T, no-max softmax (q pre-scaled; exp2-domain bounded)
// with deferred normalization, PV in four 64-k quarters through the per-wave
// ps tile, XOR-swizzled vts, bias init hoisted before the staging barrier.
// ---------------------------------------------------------------------------
__global__ __launch_bounds__(512) void attn_kernel(const bf16* __restrict__ qw,
                                                   const bf16* __restrict__ kw,
                                                   const bf16* __restrict__ vw,
                                                   const bf16* __restrict__ gw,
                                                   const float* __restrict__ pair_bias,
                                                   const float* __restrict__ mask_bias,
                                                   bf16* __restrict__ ow) {
    // bijective XCD swizzle over 2048 blocks
    const int wg = blockIdx.x;
    const int swz = ((wg & 7) << 8) + (wg >> 3);
    const int qc2 = swz & 1;
    const int n1 = (swz >> 1) & 255;
    const int h = swz >> 9;

    __shared__ bf16 klds[256][40];   // K slice [k][c], stride 20 dw
    __shared__ bf16 vts[32][256];    // V^T, col = k ^ 16*((c>>3)&3) ^ 8*(c&7)
    __shared__ bf16 ps[8][16][76];   // per-wave P tile, 64-k quarters

    const int t = threadIdx.x;

    // stage K (row-major head slice) and V^T (swizzled): 512 thr, 2 p-iters
    {
        const size_t base = ((size_t)n1 * NSEQ) * HC + (size_t)h * C;
        const int rr = t >> 2, cc4 = t & 3, ch = cc4 * 8;  // rr 0..127
        #pragma unroll
        for (int p = 0; p < 2; p++) {
            int row = p * 128 + rr;
            bf16x8 kv = *(const bf16x8*)&kw[base + (size_t)row * HC + ch];
            *(bf16x8*)&klds[row][ch] = kv;
            bf16x8 vv = *(const bf16x8*)&vw[base + (size_t)row * HC + ch];
            #pragma unroll
            for (int j = 0; j < 8; j++) {
                int colw = row ^ (cc4 << 4) ^ (j << 3);
                vts[ch + j][colw] = vv[j];
            }
        }
    }

    const int w = t >> 6, l = t & 63, lr = l & 15, lg = l >> 4;
    const int qbase = qc2 * 128 + w * 16;

    // Q fragment: A[q=lr][c = lg*8 + j]  (log2e pre-folded at projection)
    bf16x8 qf = *(const bf16x8*)&qw[((size_t)(n1 * NSEQ + qbase + lr)) * HC + h * C + lg * 8];

    const float* pb = pair_bias + (size_t)h * NSEQ * NSEQ;
    const float* mb = mask_bias + (size_t)n1 * NSEQ;

    // bias init before the barrier (pure VMEM, overlaps staging drain)
    f32x4 s[16];
    #pragma unroll
    for (int kt = 0; kt < 16; kt++) {
        float mbk = mb[kt * 16 + lr] * LOG2E;
        #pragma unroll
        for (int r = 0; r < 4; r++)
            s[kt][r] = fmaf(pb[(size_t)(qbase + lg * 4 + r) * NSEQ + kt * 16 + lr],
                            LOG2E, mbk);
    }

    __syncthreads();

    #pragma unroll
    for (int kt = 0; kt < 16; kt++) {
        bf16x8 kf = *(const bf16x8*)&klds[kt * 16 + lr][lg * 8];
        s[kt] = MFMA16(qf, kf, s[kt]);
    }

    // exp2 + row sums only (no max pass — R20-proven safe); P unnormalized
    float pinv[4];
    #pragma unroll
    for (int r = 0; r < 4; r++) {
        float sum = 0.f;
        #pragma unroll
        for (int kt = 0; kt < 16; kt++) {
            float e = __builtin_amdgcn_exp2f(s[kt][r]);
            s[kt][r] = e;
            sum += e;
        }
        #pragma unroll
        for (int msk = 8; msk >= 1; msk >>= 1) sum += __shfl_xor(sum, msk, 64);
        pinv[r] = __builtin_amdgcn_rcpf(sum);
    }

    // PV in four 64-k quarters via per-wave ps (same-wave, in-order);
    // P stored raw (normalization deferred to the gate)
    f32x4 o[2];
    o[0] = (f32x4)0.f;
    o[1] = (f32x4)0.f;
    #pragma unroll
    for (int qtr = 0; qtr < 4; qtr++) {
        #pragma unroll
        for (int kt2 = 0; kt2 < 4; kt2++) {
            #pragma unroll
            for (int r = 0; r < 4; r++)
                ps[w][lg * 4 + r][kt2 * 16 + lr] = (bf16)s[qtr * 4 + kt2][r];
        }
        #pragma unroll
        for (int kh = 0; kh < 2; kh++) {
            bf16x8 pf = *(const bf16x8*)&ps[w][lr][kh * 32 + lg * 8];
            #pragma unroll
            for (int ct = 0; ct < 2; ct++) {
                int g2 = (2 * ct + (lr >> 3)) & 3;
                int col0 = (qtr * 64 + kh * 32 + lg * 8) ^ (g2 << 4) ^ ((lr & 7) << 3);
                bf16x8 vf = *(const bf16x8*)&vts[ct * 16 + lr][col0];
                o[ct] = MFMA16(pf, vf, o[ct]);
            }
        }
    }

    // gate + deferred normalization + store head slice
    #pragma unroll
    for (int ct = 0; ct < 2; ct++) {
        #pragma unroll
        for (int r = 0; r < 4; r++) {
            size_t idx = ((size_t)(n1 * NSEQ + qbase + lg * 4 + r)) * HC + (size_t)h * C +
                         ct * 16 + lr;
            float gv = (float)gw[idx];
            ow[idx] = (bf16)(o[ct][r] * pinv[r] * gv);
        }
    }
}

// ---------------------------------------------------------------------------
// Output projection (R23-final): w_o staged f32->bf16 inline; swapped
// operands; og tiles double-buffered in LDS; float4 stores.
// ---------------------------------------------------------------------------
__global__ __launch_bounds__(512) void out_proj(const bf16* __restrict__ og,
                                                const float* __restrict__ wof,
                                                float* __restrict__ out) {
    __shared__ bf16 ws[128][136];
    __shared__ bf16 xs[2][64][136];

    const int t = threadIdx.x;
    const int row_blk = blockIdx.x * 256;
    const int sr = t >> 3, sc = (t & 7) * 16;

    #pragma unroll
    for (int i = t; i < 2048; i += 512) {
        int row = i >> 4, col = (i & 15) * 8;
        float4 a0 = *(const float4*)&wof[row * CQ + col];
        float4 a1 = *(const float4*)&wof[row * CQ + col + 4];
        *(bf16x8*)&ws[row][col] = cvt8(a0, a1);
    }
    {
        const bf16* p = og + (size_t)(row_blk + sr) * HC + sc;
        *(bf16x8*)&xs[0][sr][sc] = *(const bf16x8*)p;
        *(bf16x8*)&xs[0][sr][sc + 8] = *(const bf16x8*)(p + 8);
    }
    __syncthreads();

    const int w = t >> 6, l = t & 63, lr = l & 15, lg = l >> 4;

    bf16x8 a[4];
    #pragma unroll
    for (int ks = 0; ks < 4; ks++)
        a[ks] = *(const bf16x8*)&ws[w * 16 + lr][ks * 32 + lg * 8];

    #pragma unroll 1
    for (int it = 0; it < 4; it++) {
        const int cur = it & 1;

        bf16x8 m0, m1;
        if (it < 3) {
            const bf16* p = og + (size_t)(row_blk + (it + 1) * 64 + sr) * HC + sc;
            m0 = *(const bf16x8*)p;
            m1 = *(const bf16x8*)(p + 8);
        }

        #pragma unroll
        for (int rt = 0; rt < 4; rt++) {
            bf16x8 b[4];
            #pragma unroll
            for (int ks = 0; ks < 4; ks++)
                b[ks] = *(const bf16x8*)&xs[cur][rt * 16 + lr][ks * 32 + lg * 8];

            f32x4 acc = (f32x4)0.f;
            #pragma unroll
            for (int ks = 0; ks < 4; ks++)
                acc = MFMA16(a[ks], b[ks], acc);

            *(float4*)&out[(size_t)(row_blk + it * 64 + rt * 16 + lr) * CQ + w * 16 + lg * 4] =
                (float4){acc[0], acc[1], acc[2], acc[3]};
        }

        if (it < 3) {
            *(bf16x8*)&xs[cur ^ 1][sr][sc] = m0;
            *(bf16x8*)&xs[cur ^ 1][sr][sc + 8] = m1;
        }
        __syncthreads();
    }
}

// ---------------------------------------------------------------------------
extern "C" void kernel_launch(void* const* d_in, const int* in_sizes, int n_in,
                              void* d_out, int out_size, void* d_ws, size_t ws_size,
                              hipStream_t stream) {
    const float* q_x = (const float*)d_in[0];
    const float* kv_x = (const float*)d_in[1];
    const float* mask_bias = (const float*)d_in[2];
    const float* pair_bias = (const float*)d_in[3];
    const float* w_q = (const float*)d_in[4];
    const float* w_k = (const float*)d_in[5];
    const float* w_v = (const float*)d_in[6];
    const float* w_g = (const float*)d_in[7];
    const float* w_o = (const float*)d_in[8];

    const size_t M = (size_t)NSEQ * NSEQ;  // 65536
    bf16* qws = (bf16*)d_ws;
    bf16* gws = qws + M * HC;
    bf16* kws = gws + M * HC;
    bf16* vws = kws + M * HC;
    bf16* ows = vws + M * HC;

    proj_all<<<dim3(256, 2), 512, 0, stream>>>(q_x, kv_x, w_q, w_k, w_v, w_g,
                                               qws, gws, kws, vws);
    attn_kernel<<<dim3(2048), 512, 0, stream>>>(qws, kws, vws, gws, pair_bias,
                                                mask_bias, ows);
    out_proj<<<dim3(256), 512, 0, stream>>>(ows, w_o, (float*)d_out);
}